// Round 12
// baseline (247.677 us; speedup 1.0000x reference)
//
#include <hip/hip_runtime.h>
#include <stdint.h>
#include <math.h>

#define BLOCK 512         // 8 waves per block, 1 atom per wave
#define WPB 8
#define SEL0 46
#define SEL1 92
#define ASEL0 16
#define ASEL1 32
#define NNB 138           // SEL0+SEL1
#define NANG 48           // ASEL0+ASEL1
#define DDIM 282          // NNB + 3*NANG
#define HID 64
#define FEPS 1e-16f
#define NPT 32            // neighbors per lane (covers N<=2048)
#define CAP 128           // per-type candidate cap (wave-sortable)
#define NMAX 2048         // max N for LDS force accumulator
#define SFE (3*NMAX)      // energy accumulator slot in sF
#define RGROUPS 8         // reduce: slot groups (blockIdx.y)

__device__ __forceinline__ float mimg(float dx, float box, float ibox) {
    return dx - box * rintf(dx * ibox);   // jnp.round = round-half-even = rintf
}

// wave-synchronous "barrier": drain LDS ops + stop compiler reordering.
__device__ __forceinline__ void wsync() {
    asm volatile("s_waitcnt lgkmcnt(0)" ::: "memory");
    __builtin_amdgcn_wave_barrier();
}

__device__ __forceinline__ void decode(unsigned long long k, float& d, int& j) {
    uint32_t idx = (uint32_t)(k & 0xFFFFFFFFull);
    if (idx == 0xFFFFFFFFu) { d = 1e30f; j = -1; }
    else { d = __uint_as_float((uint32_t)(k >> 32)); j = (int)idx; }
}

// per-batch stable type-partition of atom indices: type-0 atoms first.
// one wave per batch (ballot/popc compaction, 2 passes).
__global__ __launch_bounds__(64)
void order_kernel(const int* __restrict__ T, int* __restrict__ order,
                  int B, int N)
{
    int b = blockIdx.x;
    if (b >= B) return;
    const int lane = threadIdx.x & 63;
    const int* Tb = T + (size_t)b * N;
    int* ob = order + (size_t)b * N;
    const unsigned long long lmlt = (1ull << lane) - 1ull;
    int cnt0 = 0;
    for (int j0 = 0; j0 < N; j0 += 64) {
        int j = j0 + lane;
        bool p0 = (j < N) && (Tb[j] == 0);
        cnt0 += (int)__popcll(__ballot(p0));
    }
    int base0 = 0, base1 = cnt0;
    for (int j0 = 0; j0 < N; j0 += 64) {
        int j = j0 + lane;
        bool valid = (j < N);
        bool p0 = valid && (Tb[j] == 0);
        bool p1 = valid && (Tb[j] != 0);
        unsigned long long m0 = __ballot(p0), m1 = __ballot(p1);
        if (p0) ob[base0 + __popcll(m0 & lmlt)] = j;
        if (p1) ob[base1 + __popcll(m1 & lmlt)] = j;
        base0 += (int)__popcll(m0);
        base1 += (int)__popcll(m1);
    }
}

// sum per-block slots -> out (atomic partials).  out = [energy(B) | forces(3BN)]
__global__ __launch_bounds__(256)
void reduce_kernel(const float* __restrict__ rep, float* __restrict__ out,
                   int total, int B, int N, int sstride, int nspb, int rgs)
{
    int e = blockIdx.x * 256 + threadIdx.x;
    if (e >= total) return;
    int r0 = blockIdx.y * rgs;
    if (r0 >= nspb) return;
    int r1 = min(r0 + rgs, nspb);
    const float* p;
    if (e < B) {
        p = rep + (size_t)e * nspb * sstride + 3 * N;
    } else {
        int f = e - B;
        int b = f / (3 * N);
        int elem = f - b * 3 * N;
        p = rep + (size_t)b * nspb * sstride + elem;
    }
    p += (size_t)r0 * sstride;
    float s0=0,s1=0,s2=0,s3=0,s4=0,s5=0,s6=0,s7=0;
    int r = r0;
    const size_t st = (size_t)sstride;
    for (; r + 8 <= r1; r += 8) {
        s0 += p[0*st]; s1 += p[1*st]; s2 += p[2*st]; s3 += p[3*st];
        s4 += p[4*st]; s5 += p[5*st]; s6 += p[6*st]; s7 += p[7*st];
        p += 8*st;
    }
    float s = ((s0+s1)+(s2+s3)) + ((s4+s5)+(s6+s7));
    for (; r < r1; ++r) { s += *p; p += st; }
    atomicAdd(&out[e], s);
}

__global__ __launch_bounds__(BLOCK, 4)
void md_kernel(const float* __restrict__ xyz, const int* __restrict__ types,
               const void* __restrict__ boxp,
               const float* __restrict__ W0a, const float* __restrict__ B0a,
               const float* __restrict__ W1a, const float* __restrict__ B1a,
               const float* __restrict__ W2a, const float* __restrict__ B2a,
               const float* __restrict__ W0b, const float* __restrict__ B0b,
               const float* __restrict__ W1b, const float* __restrict__ B1b,
               const float* __restrict__ W2b, const float* __restrict__ B2b,
               const int* __restrict__ order,
               float* __restrict__ out, float* __restrict__ slotbase,
               int sstride, int B, int N)
{
    __shared__ unsigned long long A0s[WPB][CAP];
    __shared__ unsigned long long A1s[WPB][CAP];
    __shared__ float sdescs[WPB][DDIM];
    __shared__ float sgs[WPB][DDIM];
    __shared__ float sAs[WPB][9];
    __shared__ float sh1s[WPB][HID];
    __shared__ float sdh1s[WPB][HID];
    __shared__ float sF[3*NMAX + 8];   // block-local force accumulator (+energy)

    const int w = threadIdx.x >> 6;
    const int lane = threadIdx.x & 63;
    const bool lmode = (slotbase != nullptr);

    // zero the block force accumulator, then full-block barrier
    for (int s2 = threadIdx.x; s2 <= SFE; s2 += BLOCK) sF[s2] = 0.0f;
    __syncthreads();

    const int slotA = blockIdx.x * WPB + w;
    if (slotA < B * N) {
        unsigned long long* A0w = A0s[w];
        unsigned long long* A1w = A1s[w];
        float* sdescw = sdescs[w];
        float* sgw = sgs[w];
        float* sAw = sAs[w];
        float* sh1w = sh1s[w];
        float* sdh1w = sdh1s[w];

        const int b = slotA / N;
        // type-sorted remap: all 8 atoms of this block share one weight set
        const int i = order ? order[(size_t)b * N + (slotA - b * N)]
                            : (slotA - b * N);

        // box_size may arrive as int32 or float32; decode.
        int ib_test = ((const int*)boxp)[0];
        float box = (ib_test > 0 && ib_test < 1000000) ? (float)ib_test
                                                       : ((const float*)boxp)[0];
        float ibox = 1.0f / box;

        const float* X = xyz + (size_t)b * N * 3;
        const int*   T = types + (size_t)b * N;
        const int ti = T[i];
        const float xi = X[3*i+0], yi = X[3*i+1], zi = X[3*i+2];
        float* Fg = out + B + (size_t)3 * b * N;   // fallback force base

        // ---- per-lane distance keys: rk = typebit<<31 | dist_bits ----
        uint32_t rk[NPT];
        #pragma unroll
        for (int jj = 0; jj < NPT; ++jj) {
            int j = jj * 64 + lane;
            uint32_t k = 0x7FFFFFFFu;        // self / pad: never below threshold
            if (j < N && j != i) {
                float dx = mimg(xi - X[3*j+0], box, ibox);
                float dy = mimg(yi - X[3*j+1], box, ibox);
                float dz = mimg(zi - X[3*j+2], box, ibox);
                float d = sqrtf(dx*dx + dy*dy + dz*dz);
                k = __float_as_uint(d) | (T[j] ? 0x80000000u : 0u);
            }
            rk[jj] = k;
        }

        // ---- per-type totals via ballot+popc ----
        uint32_t t1 = 0;
        #pragma unroll
        for (int jj = 0; jj < NPT; ++jj)
            t1 += (uint32_t)__popcll(__ballot((rk[jj] >> 31) != 0u));
        const int tot1 = (int)t1;
        const int tot0 = (N - 1) - tot1;
        const int need0 = min(SEL0, tot0);
        const int need1 = min(SEL1, tot1);

        // ---- density-guess radii; fused count+compact; retry only if off ----
        const float vol = box * box * box;
        const float c43pi = 4.18879020f;   // 4/3*pi
        float R0 = cbrtf(0.5f * (need0 + CAP) * vol / (c43pi * fmaxf((float)tot0, 1.0f)));
        float R1 = cbrtf(0.5f * (need1 + CAP) * vol / (c43pi * fmaxf((float)tot1, 1.0f)));
        float lo0 = 0.0f, hi0 = -1.0f, lo1 = 0.0f, hi1 = -1.0f;
        const unsigned long long lmlt = (1ull << lane) - 1ull;
        int c0n = 0, c1n = 0;
        for (int it = 0; it < 20; ++it) {
            uint32_t Rb0 = __float_as_uint(R0), Rb1 = __float_as_uint(R1);
            int base0 = 0, base1 = 0;
            #pragma unroll
            for (int jj = 0; jj < NPT; ++jj) {
                uint32_t k = rk[jj];
                bool p0 = (k < 0x80000000u) && (k < Rb0);
                bool p1 = (k >= 0x80000000u) && ((k & 0x7FFFFFFFu) < Rb1);
                unsigned long long m0 = __ballot(p0);
                unsigned long long m1 = __ballot(p1);
                if (p0) {
                    int pos = base0 + __popcll(m0 & lmlt);
                    if (pos < CAP)
                        A0w[pos] = ((unsigned long long)k << 32) | (uint32_t)(jj*64 + lane);
                }
                if (p1) {
                    int pos = base1 + __popcll(m1 & lmlt);
                    if (pos < CAP)
                        A1w[pos] = ((unsigned long long)(k & 0x7FFFFFFFu) << 32) | (uint32_t)(jj*64 + lane);
                }
                base0 += __popcll(m0);
                base1 += __popcll(m1);
            }
            bool ok0 = (base0 >= need0 && base0 <= CAP);
            bool ok1 = (base1 >= need1 && base1 <= CAP);
            c0n = min(base0, CAP);
            c1n = min(base1, CAP);
            if (ok0 && ok1) break;
            if (!ok0) {
                if (base0 < need0) { lo0 = R0; R0 = (hi0 > 0.0f) ? 0.5f*(lo0+hi0) : R0*1.3f; }
                else               { hi0 = R0; R0 = 0.5f*(lo0+hi0); }
            }
            if (!ok1) {
                if (base1 < need1) { lo1 = R1; R1 = (hi1 > 0.0f) ? 0.5f*(lo1+hi1) : R1*1.3f; }
                else               { hi1 = R1; R1 = 0.5f*(lo1+hi1); }
            }
        }
        #pragma unroll
        for (int t = lane; t < CAP; t += 64) {
            if (t >= c0n) A0w[t] = ~0ull;
            if (t >= c1n) A1w[t] = ~0ull;
        }
        wsync();

        // ---- dual 128-element register bitonic sort ----
        {
            unsigned long long va = A0w[lane], vb = A0w[lane + 64];
            unsigned long long wa = A1w[lane], wb = A1w[lane + 64];
            #pragma unroll
            for (int size = 2; size <= 128; size <<= 1) {
                #pragma unroll
                for (int stride = 64; stride > 0; stride >>= 1) {
                    if (stride >= size) continue;
                    if (stride == 64) {
                        unsigned long long mn = va < vb ? va : vb;
                        unsigned long long mx = va < vb ? vb : va;
                        va = mn; vb = mx;
                        mn = wa < wb ? wa : wb;
                        mx = wa < wb ? wb : wa;
                        wa = mn; wb = mx;
                    } else {
                        bool keep_lo = (lane & stride) == 0;
                        bool asc0 = ((lane & size) == 0);
                        bool asc1 = (((lane + 64) & size) == 0);
                        unsigned long long oa = __shfl_xor(va, stride, 64);
                        unsigned long long ob = __shfl_xor(vb, stride, 64);
                        va = (asc0 == keep_lo) ? (va < oa ? va : oa) : (va > oa ? va : oa);
                        vb = (asc1 == keep_lo) ? (vb < ob ? vb : ob) : (vb > ob ? vb : ob);
                        oa = __shfl_xor(wa, stride, 64);
                        ob = __shfl_xor(wb, stride, 64);
                        wa = (asc0 == keep_lo) ? (wa < oa ? wa : oa) : (wa > oa ? wa : oa);
                        wb = (asc1 == keep_lo) ? (wb < ob ? wb : ob) : (wb > ob ? wb : ob);
                    }
                }
            }
            A0w[lane] = va; A0w[lane + 64] = vb;
            A1w[lane] = wa; A1w[lane + 64] = wb;
        }
        wsync();

        // ---- radial features 1/(d+eps) ----
        for (int t = lane; t < NNB; t += 64) {
            unsigned long long k = (t < SEL0) ? A0w[t] : A1w[t - SEL0];
            float d; int j; decode(k, d, j);
            sdescw[t] = 1.0f / (d + FEPS);
        }

        // ---- local frame (lane 0) ----
        float f_ld0 = 1.0f, f_ld1 = 1.0f; int f_j0 = -1, f_j1 = -1;
        float r0x=0,r0y=0,r0z=0, r1x=0,r1y=0,r1z=0;
        float u0x=0,u0y=0,u0z=0, u1x=0,u1y=0,u1z=0;
        float f_s=0, f_n2=1, f_n3=1;
        float e2x=0,e2y=0,e2z=0, e3x=0,e3y=0,e3z=0;
        if (lane == 0) {
            float da0, da1, db0, db1; int ja0, ja1, jb0, jb1;
            decode(A0w[0], da0, ja0);
            decode(A0w[1], da1, ja1);
            decode(A1w[0], db0, jb0);
            decode(A1w[1], db1, jb1);
            f_ld0 = (db0 < da0) ? db0 : da0;  f_j0 = (db0 < da0) ? jb0 : ja0;
            f_ld1 = (db1 < da1) ? db1 : da1;  f_j1 = (db1 < da1) ? jb1 : ja1;
            if (f_j0 < 0) f_j0 = i;
            if (f_j1 < 0) f_j1 = i;
            u0x = mimg(xi - X[3*f_j0+0], box, ibox);
            u0y = mimg(yi - X[3*f_j0+1], box, ibox);
            u0z = mimg(zi - X[3*f_j0+2], box, ibox);
            u1x = mimg(xi - X[3*f_j1+0], box, ibox);
            u1y = mimg(yi - X[3*f_j1+1], box, ibox);
            u1z = mimg(zi - X[3*f_j1+2], box, ibox);
            float id0 = 1.0f/(f_ld0 + FEPS), id1 = 1.0f/(f_ld1 + FEPS);
            r0x = u0x*id0; r0y = u0y*id0; r0z = u0z*id0;
            r1x = u1x*id1; r1y = u1y*id1; r1z = u1z*id1;
            f_s = r0x*r1x + r0y*r1y + r0z*r1z;
            float v2x = r1x - f_s*r0x, v2y = r1y - f_s*r0y, v2z = r1z - f_s*r0z;
            f_n2 = sqrtf(v2x*v2x + v2y*v2y + v2z*v2z);
            e2x = v2x/f_n2; e2y = v2y/f_n2; e2z = v2z/f_n2;
            float cx = r0y*r1z - r0z*r1y;
            float cy = r0z*r1x - r0x*r1z;
            float cz = r0x*r1y - r0y*r1x;
            f_n3 = sqrtf(cx*cx + cy*cy + cz*cz);
            e3x = cx/f_n3; e3y = cy/f_n3; e3z = cz/f_n3;
            sAw[0]=r0x; sAw[1]=r0y; sAw[2]=r0z;
            sAw[3]=e2x; sAw[4]=e2y; sAw[5]=e2z;
            sAw[6]=e3x; sAw[7]=e3y; sAw[8]=e3z;
        }
        wsync();

        // ---- angular features: f = (A . dm) / (d+eps)^2 ----
        if (lane < NANG) {
            int slot = (lane < ASEL0) ? lane : SEL0 + (lane - ASEL0);
            unsigned long long k = (slot < SEL0) ? A0w[slot] : A1w[slot - SEL0];
            float d; int j; decode(k, d, j);
            float dx = 0, dy = 0, dz = 0;
            if (j >= 0) {
                dx = mimg(xi - X[3*j+0], box, ibox);
                dy = mimg(yi - X[3*j+1], box, ibox);
                dz = mimg(zi - X[3*j+2], box, ibox);
            }
            float de = d + FEPS;
            float q = 1.0f/(de*de);
            float wx = sAw[0]*dx + sAw[1]*dy + sAw[2]*dz;
            float wy = sAw[3]*dx + sAw[4]*dy + sAw[5]*dz;
            float wz = sAw[6]*dx + sAw[7]*dy + sAw[8]*dz;
            sdescw[NNB + 3*lane + 0] = wx*q;
            sdescw[NNB + 3*lane + 1] = wy*q;
            sdescw[NNB + 3*lane + 2] = wz*q;
        }
        wsync();

        // ---- MLP forward + backward: lane = neuron ----
        const float* W0 = ti ? W0b : W0a;  const float* B0 = ti ? B0b : B0a;
        const float* W1 = ti ? W1b : W1a;  const float* B1 = ti ? B1b : B1a;
        const float* W2 = ti ? W2b : W2a;  const float* B2 = ti ? B2b : B2a;

        float a0 = 0.0f, a1 = 0.0f, a2 = 0.0f, a3 = 0.0f;
        for (int d = 0; d < DDIM - 2; d += 4) {
            a0 = fmaf(sdescw[d+0], W0[(d+0)*HID + lane], a0);
            a1 = fmaf(sdescw[d+1], W0[(d+1)*HID + lane], a1);
            a2 = fmaf(sdescw[d+2], W0[(d+2)*HID + lane], a2);
            a3 = fmaf(sdescw[d+3], W0[(d+3)*HID + lane], a3);
        }
        a0 = fmaf(sdescw[DDIM-2], W0[(DDIM-2)*HID + lane], a0);
        a1 = fmaf(sdescw[DDIM-1], W0[(DDIM-1)*HID + lane], a1);
        float h1 = tanhf(B0[lane] + ((a0 + a1) + (a2 + a3)));
        sh1w[lane] = h1;
        wsync();

        float acc2 = B1[lane];
        #pragma unroll
        for (int m = 0; m < HID; ++m) acc2 = fmaf(sh1w[m], W1[m*HID + lane], acc2);
        float h2 = tanhf(acc2);
        float w2v = W2[lane];
        float part = h2 * w2v;
        #pragma unroll
        for (int o = 32; o > 0; o >>= 1) part += __shfl_down(part, o, 64);
        if (lane == 0) {
            if (lmode) atomicAdd(&sF[SFE], part + B2[0]);
            else       atomicAdd(&out[b], part + B2[0]);
        }
        float dh2 = (1.0f - h2*h2) * w2v;
        sdh1w[lane] = dh2;
        wsync();

        float accb = 0.0f;
        #pragma unroll
        for (int m = 0; m < HID; ++m) accb = fmaf(W1[lane*HID + m], sdh1w[m], accb);
        wsync();
        float dh1 = (1.0f - h1*h1) * accb;
        sdh1w[lane] = dh1;
        wsync();

        for (int d = lane; d < DDIM; d += 64) {
            float a = 0.0f;
            #pragma unroll
            for (int m = 0; m < HID; ++m) a = fmaf(W0[d*HID + m], sdh1w[m], a);
            sgw[d] = a;
        }
        wsync();

        // ---- gradient scatter into LDS (lmode) or global (fallback) ----
        float rG[9];
        #pragma unroll
        for (int q9 = 0; q9 < 9; ++q9) rG[q9] = 0.0f;
        float fix = 0.0f, fiy = 0.0f, fiz = 0.0f;

        for (int t = lane; t < NNB; t += 64) {
            unsigned long long k = (t < SEL0) ? A0w[t] : A1w[t - SEL0];
            float d; int j; decode(k, d, j);
            if (j >= 0) {
                float dx = mimg(xi - X[3*j+0], box, ibox);
                float dy = mimg(yi - X[3*j+1], box, ibox);
                float dz = mimg(zi - X[3*j+2], box, ibox);
                float gr = sgw[t];
                float de = d + FEPS;
                float coef = -gr / (d * de * de);
                float gx = coef*dx, gy = coef*dy, gz = coef*dz;
                int a = -1;
                if (t < ASEL0) a = t;
                else if (t >= SEL0 && t < SEL0 + ASEL1) a = ASEL0 + (t - SEL0);
                if (a >= 0) {
                    float q = 1.0f/(de*de);
                    float gax = sgw[NNB+3*a+0], gay = sgw[NNB+3*a+1], gaz = sgw[NNB+3*a+2];
                    float wx = sAw[0]*dx + sAw[1]*dy + sAw[2]*dz;
                    float wy = sAw[3]*dx + sAw[4]*dy + sAw[5]*dz;
                    float wz = sAw[6]*dx + sAw[7]*dy + sAw[8]*dz;
                    float tx = sAw[0]*gax + sAw[3]*gay + sAw[6]*gaz;
                    float ty = sAw[1]*gax + sAw[4]*gay + sAw[7]*gaz;
                    float tz = sAw[2]*gax + sAw[5]*gay + sAw[8]*gaz;
                    float gw = gax*wx + gay*wy + gaz*wz;
                    float c2 = -2.0f * gw * q / (de * d);
                    gx += q*tx + c2*dx;
                    gy += q*ty + c2*dy;
                    gz += q*tz + c2*dz;
                    rG[0] += gax*dx*q; rG[1] += gax*dy*q; rG[2] += gax*dz*q;
                    rG[3] += gay*dx*q; rG[4] += gay*dy*q; rG[5] += gay*dz*q;
                    rG[6] += gaz*dx*q; rG[7] += gaz*dy*q; rG[8] += gaz*dz*q;
                }
                if (lmode) {
                    atomicAdd(&sF[3*j+0], gx);
                    atomicAdd(&sF[3*j+1], gy);
                    atomicAdd(&sF[3*j+2], gz);
                } else {
                    atomicAdd(&Fg[3*j+0], gx);
                    atomicAdd(&Fg[3*j+1], gy);
                    atomicAdd(&Fg[3*j+2], gz);
                }
                fix -= gx; fiy -= gy; fiz -= gz;
            }
        }

        // wave-reduce frame gradients + self-force to lane 0
        #pragma unroll
        for (int o = 32; o > 0; o >>= 1) {
            #pragma unroll
            for (int q9 = 0; q9 < 9; ++q9) rG[q9] += __shfl_down(rG[q9], o, 64);
            fix += __shfl_down(fix, o, 64);
            fiy += __shfl_down(fiy, o, 64);
            fiz += __shfl_down(fiz, o, 64);
        }

        // ---- frame backward + self-force (lane 0) ----
        if (lane == 0) {
            float g0x=rG[0], g0y=rG[1], g0z=rG[2];
            float g2x=rG[3], g2y=rG[4], g2z=rG[5];
            float g3x=rG[6], g3y=rG[7], g3z=rG[8];
            float d3 = g3x*e3x + g3y*e3y + g3z*e3z;
            float in3 = 1.0f/f_n3;
            float dcx = (g3x - d3*e3x)*in3;
            float dcy = (g3y - d3*e3y)*in3;
            float dcz = (g3z - d3*e3z)*in3;
            float gr0x = r1y*dcz - r1z*dcy;
            float gr0y = r1z*dcx - r1x*dcz;
            float gr0z = r1x*dcy - r1y*dcx;
            float gr1x = dcy*r0z - dcz*r0y;
            float gr1y = dcz*r0x - dcx*r0z;
            float gr1z = dcx*r0y - dcy*r0x;
            float d2 = g2x*e2x + g2y*e2y + g2z*e2z;
            float in2 = 1.0f/f_n2;
            float dvx = (g2x - d2*e2x)*in2;
            float dvy = (g2y - d2*e2y)*in2;
            float dvz = (g2z - d2*e2z)*in2;
            gr1x += dvx; gr1y += dvy; gr1z += dvz;
            gr0x -= f_s*dvx; gr0y -= f_s*dvy; gr0z -= f_s*dvz;
            float dss = -(dvx*r0x + dvy*r0y + dvz*r0z);
            gr0x += dss*r1x; gr0y += dss*r1y; gr0z += dss*r1z;
            gr1x += dss*r0x; gr1y += dss*r0y; gr1z += dss*r0z;
            gr0x += g0x; gr0y += g0y; gr0z += g0z;
            float de0 = f_ld0 + FEPS;
            float dot0 = gr0x*u0x + gr0y*u0y + gr0z*u0z;
            float k0 = dot0 / (f_ld0 * de0 * de0);
            float gu0x = gr0x/de0 - k0*u0x;
            float gu0y = gr0y/de0 - k0*u0y;
            float gu0z = gr0z/de0 - k0*u0z;
            float de1 = f_ld1 + FEPS;
            float dot1 = gr1x*u1x + gr1y*u1y + gr1z*u1z;
            float k1 = dot1 / (f_ld1 * de1 * de1);
            float gu1x = gr1x/de1 - k1*u1x;
            float gu1y = gr1y/de1 - k1*u1y;
            float gu1z = gr1z/de1 - k1*u1z;
            fix -= gu0x + gu1x;
            fiy -= gu0y + gu1y;
            fiz -= gu0z + gu1z;
            if (lmode) {
                atomicAdd(&sF[3*f_j0+0], gu0x); atomicAdd(&sF[3*f_j0+1], gu0y); atomicAdd(&sF[3*f_j0+2], gu0z);
                atomicAdd(&sF[3*f_j1+0], gu1x); atomicAdd(&sF[3*f_j1+1], gu1y); atomicAdd(&sF[3*f_j1+2], gu1z);
                atomicAdd(&sF[3*i+0], fix);     atomicAdd(&sF[3*i+1], fiy);     atomicAdd(&sF[3*i+2], fiz);
            } else {
                atomicAdd(&Fg[3*f_j0+0], gu0x); atomicAdd(&Fg[3*f_j0+1], gu0y); atomicAdd(&Fg[3*f_j0+2], gu0z);
                atomicAdd(&Fg[3*f_j1+0], gu1x); atomicAdd(&Fg[3*f_j1+1], gu1y); atomicAdd(&Fg[3*f_j1+2], gu1z);
                atomicAdd(&Fg[3*i+0], fix);     atomicAdd(&Fg[3*i+1], fiy);     atomicAdd(&Fg[3*i+2], fiz);
            }
        }
    } // atom valid

    // ---- flush block force accumulator to its private slot ----
    __syncthreads();
    if (lmode) {
        float* slotp = slotbase + (size_t)blockIdx.x * sstride;
        for (int s2 = threadIdx.x; s2 < 3*N; s2 += BLOCK) slotp[s2] = sF[s2];
        if (threadIdx.x == 0) slotp[3*N] = sF[SFE];
    }
}

extern "C" void kernel_launch(void* const* d_in, const int* in_sizes, int n_in,
                              void* d_out, int out_size, void* d_ws, size_t ws_size,
                              hipStream_t stream) {
    const float* xyz  = (const float*)d_in[0];
    const int*   types = (const int*)d_in[1];
    const void*  boxp = d_in[2];
    int BN = in_sizes[1];              // B*N
    int B = out_size - 3*BN;           // out = energy(B) + forces(3*B*N)
    if (B < 1) B = 1;
    int N = BN / B;

    // workspace: [order BN ints][per-block slots]
    int sstride = 3 * N + 32;
    size_t obytes = ((size_t)BN * sizeof(int) + 255) & ~(size_t)255;
    size_t slotbytes = (size_t)(BN / WPB) * sstride * sizeof(float);
    bool ok = (N <= NMAX) && (N % WPB == 0) && (BN % WPB == 0) &&
              (obytes + slotbytes <= ws_size);

    // out is accumulated atomically (reduce partials / fallback) -> zero it
    hipMemsetAsync(d_out, 0, (size_t)out_size * sizeof(float), stream);

    if (ok) {
        int*   order = (int*)d_ws;
        float* rep   = (float*)((char*)d_ws + obytes);
        order_kernel<<<dim3(B), dim3(64), 0, stream>>>(types, order, B, N);
        int nblk = BN / WPB;           // 512 blocks at B=2,N=2048
        md_kernel<<<dim3(nblk), dim3(BLOCK), 0, stream>>>(
            xyz, types, boxp,
            (const float*)d_in[3],  (const float*)d_in[4],
            (const float*)d_in[5],  (const float*)d_in[6],
            (const float*)d_in[7],  (const float*)d_in[8],
            (const float*)d_in[9],  (const float*)d_in[10],
            (const float*)d_in[11], (const float*)d_in[12],
            (const float*)d_in[13], (const float*)d_in[14],
            order,
            (float*)d_out, rep, sstride, B, N);
        int nspb = N / WPB;            // slots per batch
        int ngroups = (nspb < RGROUPS) ? nspb : RGROUPS;
        int rgs = (nspb + ngroups - 1) / ngroups;
        int nb = (out_size + 255) / 256;
        reduce_kernel<<<dim3(nb, ngroups), dim3(256), 0, stream>>>(
            rep, (float*)d_out, out_size, B, N, sstride, nspb, rgs);
    } else {
        // fallback: device-scope atomics straight into out, identity order
        int nblk = (BN + WPB - 1) / WPB;
        md_kernel<<<dim3(nblk), dim3(BLOCK), 0, stream>>>(
            xyz, types, boxp,
            (const float*)d_in[3],  (const float*)d_in[4],
            (const float*)d_in[5],  (const float*)d_in[6],
            (const float*)d_in[7],  (const float*)d_in[8],
            (const float*)d_in[9],  (const float*)d_in[10],
            (const float*)d_in[11], (const float*)d_in[12],
            (const float*)d_in[13], (const float*)d_in[14],
            nullptr,
            (float*)d_out, nullptr, 0, B, N);
    }
}

// Round 13
// 227.865 us; speedup vs baseline: 1.0869x; 1.0869x over previous
//
#include <hip/hip_runtime.h>
#include <stdint.h>
#include <math.h>

#define BLOCK 512         // 8 waves per block, 1 atom per wave
#define WPB 8
#define SEL0 46
#define SEL1 92
#define ASEL0 16
#define ASEL1 32
#define NNB 138           // SEL0+SEL1
#define NANG 48           // ASEL0+ASEL1
#define DDIM 282          // NNB + 3*NANG
#define HID 64
#define FEPS 1e-16f
#define NPT 32            // neighbors per lane (covers N<=2048)
#define CAP 128           // per-type candidate cap (wave-sortable)
#define NMAX 2048         // max N for LDS force accumulator
#define SFE (3*NMAX)      // energy accumulator slot in sF
#define RGROUPS 8         // reduce: slot groups (blockIdx.y)

__device__ __forceinline__ float mimg(float dx, float box, float ibox) {
    return dx - box * rintf(dx * ibox);   // jnp.round = round-half-even = rintf
}

// wave-synchronous "barrier": drain LDS ops + stop compiler reordering.
__device__ __forceinline__ void wsync() {
    asm volatile("s_waitcnt lgkmcnt(0)" ::: "memory");
    __builtin_amdgcn_wave_barrier();
}

__device__ __forceinline__ void decode(unsigned long long k, float& d, int& j) {
    uint32_t idx = (uint32_t)(k & 0xFFFFFFFFull);
    if (idx == 0xFFFFFFFFu) { d = 1e30f; j = -1; }
    else { d = __uint_as_float((uint32_t)(k >> 32)); j = (int)idx; }
}

// sum per-block slots -> out (atomic partials).  out = [energy(B) | forces(3BN)]
// slot r: [forces 3N][energy at 3N].  batch(r) = r/nspb.
__global__ __launch_bounds__(256)
void reduce_kernel(const float* __restrict__ rep, float* __restrict__ out,
                   int total, int B, int N, int sstride, int nspb, int rgs)
{
    int e = blockIdx.x * 256 + threadIdx.x;
    if (e >= total) return;
    int r0 = blockIdx.y * rgs;
    if (r0 >= nspb) return;
    int r1 = min(r0 + rgs, nspb);
    const float* p;
    if (e < B) {
        p = rep + (size_t)e * nspb * sstride + 3 * N;
    } else {
        int f = e - B;
        int b = f / (3 * N);
        int elem = f - b * 3 * N;
        p = rep + (size_t)b * nspb * sstride + elem;
    }
    p += (size_t)r0 * sstride;
    float s0=0,s1=0,s2=0,s3=0,s4=0,s5=0,s6=0,s7=0;
    int r = r0;
    const size_t st = (size_t)sstride;
    for (; r + 8 <= r1; r += 8) {
        s0 += p[0*st]; s1 += p[1*st]; s2 += p[2*st]; s3 += p[3*st];
        s4 += p[4*st]; s5 += p[5*st]; s6 += p[6*st]; s7 += p[7*st];
        p += 8*st;
    }
    float s = ((s0+s1)+(s2+s3)) + ((s4+s5)+(s6+s7));
    for (; r < r1; ++r) { s += *p; p += st; }
    atomicAdd(&out[e], s);
}

__global__ __launch_bounds__(BLOCK, 4)
void md_kernel(const float* __restrict__ xyz, const int* __restrict__ types,
               const void* __restrict__ boxp,
               const float* __restrict__ W0a, const float* __restrict__ B0a,
               const float* __restrict__ W1a, const float* __restrict__ B1a,
               const float* __restrict__ W2a, const float* __restrict__ B2a,
               const float* __restrict__ W0b, const float* __restrict__ B0b,
               const float* __restrict__ W1b, const float* __restrict__ B1b,
               const float* __restrict__ W2b, const float* __restrict__ B2b,
               float* __restrict__ out, float* __restrict__ slotbase,
               int sstride, int B, int N)
{
    __shared__ unsigned long long A0s[WPB][CAP];
    __shared__ unsigned long long A1s[WPB][CAP];
    __shared__ float sdescs[WPB][DDIM];
    __shared__ float sgs[WPB][DDIM];
    __shared__ float sAs[WPB][9];
    __shared__ float sh1s[WPB][HID];
    __shared__ float sdh1s[WPB][HID];
    __shared__ float sF[3*NMAX + 8];   // block-local force accumulator (+energy)

    const int w = threadIdx.x >> 6;
    const int lane = threadIdx.x & 63;
    const bool lmode = (slotbase != nullptr);

    // zero the block force accumulator, then full-block barrier
    for (int s2 = threadIdx.x; s2 <= SFE; s2 += BLOCK) sF[s2] = 0.0f;
    __syncthreads();

    const int atom = blockIdx.x * WPB + w;
    if (atom < B * N) {
        unsigned long long* A0w = A0s[w];
        unsigned long long* A1w = A1s[w];
        float* sdescw = sdescs[w];
        float* sgw = sgs[w];
        float* sAw = sAs[w];
        float* sh1w = sh1s[w];
        float* sdh1w = sdh1s[w];

        const int b = atom / N;
        const int i = atom - b * N;

        // box_size may arrive as int32 or float32; decode.
        int ib_test = ((const int*)boxp)[0];
        float box = (ib_test > 0 && ib_test < 1000000) ? (float)ib_test
                                                       : ((const float*)boxp)[0];
        float ibox = 1.0f / box;

        const float* X = xyz + (size_t)b * N * 3;
        const int*   T = types + (size_t)b * N;
        const int ti = T[i];
        const float xi = X[3*i+0], yi = X[3*i+1], zi = X[3*i+2];
        float* Fg = out + B + (size_t)3 * b * N;   // fallback force base

        // ---- per-lane distance keys: rk = typebit<<31 | dist_bits ----
        uint32_t rk[NPT];
        #pragma unroll
        for (int jj = 0; jj < NPT; ++jj) {
            int j = jj * 64 + lane;
            uint32_t k = 0x7FFFFFFFu;        // self / pad: never below threshold
            if (j < N && j != i) {
                float dx = mimg(xi - X[3*j+0], box, ibox);
                float dy = mimg(yi - X[3*j+1], box, ibox);
                float dz = mimg(zi - X[3*j+2], box, ibox);
                float d = sqrtf(dx*dx + dy*dy + dz*dz);
                k = __float_as_uint(d) | (T[j] ? 0x80000000u : 0u);
            }
            rk[jj] = k;
        }

        // ---- per-type totals via ballot+popc (scalar pipe, no shfl chain) ----
        uint32_t t1 = 0;
        #pragma unroll
        for (int jj = 0; jj < NPT; ++jj)
            t1 += (uint32_t)__popcll(__ballot((rk[jj] >> 31) != 0u));
        const int tot1 = (int)t1;
        const int tot0 = (N - 1) - tot1;
        const int need0 = min(SEL0, tot0);
        const int need1 = min(SEL1, tot1);

        // ---- density-guess radii; fused count+compact; retry only if off ----
        const float vol = box * box * box;
        const float c43pi = 4.18879020f;   // 4/3*pi
        float R0 = cbrtf(0.5f * (need0 + CAP) * vol / (c43pi * fmaxf((float)tot0, 1.0f)));
        float R1 = cbrtf(0.5f * (need1 + CAP) * vol / (c43pi * fmaxf((float)tot1, 1.0f)));
        float lo0 = 0.0f, hi0 = -1.0f, lo1 = 0.0f, hi1 = -1.0f;
        const unsigned long long lmlt = (1ull << lane) - 1ull;
        int c0n = 0, c1n = 0;
        for (int it = 0; it < 20; ++it) {
            uint32_t Rb0 = __float_as_uint(R0), Rb1 = __float_as_uint(R1);
            int base0 = 0, base1 = 0;
            #pragma unroll
            for (int jj = 0; jj < NPT; ++jj) {
                uint32_t k = rk[jj];
                bool p0 = (k < 0x80000000u) && (k < Rb0);
                bool p1 = (k >= 0x80000000u) && ((k & 0x7FFFFFFFu) < Rb1);
                unsigned long long m0 = __ballot(p0);
                unsigned long long m1 = __ballot(p1);
                if (p0) {
                    int pos = base0 + __popcll(m0 & lmlt);
                    if (pos < CAP)
                        A0w[pos] = ((unsigned long long)k << 32) | (uint32_t)(jj*64 + lane);
                }
                if (p1) {
                    int pos = base1 + __popcll(m1 & lmlt);
                    if (pos < CAP)
                        A1w[pos] = ((unsigned long long)(k & 0x7FFFFFFFu) << 32) | (uint32_t)(jj*64 + lane);
                }
                base0 += __popcll(m0);
                base1 += __popcll(m1);
            }
            bool ok0 = (base0 >= need0 && base0 <= CAP);
            bool ok1 = (base1 >= need1 && base1 <= CAP);
            c0n = min(base0, CAP);
            c1n = min(base1, CAP);
            if (ok0 && ok1) break;
            if (!ok0) {
                if (base0 < need0) { lo0 = R0; R0 = (hi0 > 0.0f) ? 0.5f*(lo0+hi0) : R0*1.3f; }
                else               { hi0 = R0; R0 = 0.5f*(lo0+hi0); }
            }
            if (!ok1) {
                if (base1 < need1) { lo1 = R1; R1 = (hi1 > 0.0f) ? 0.5f*(lo1+hi1) : R1*1.3f; }
                else               { hi1 = R1; R1 = 0.5f*(lo1+hi1); }
            }
        }
        #pragma unroll
        for (int t = lane; t < CAP; t += 64) {
            if (t >= c0n) A0w[t] = ~0ull;
            if (t >= c1n) A1w[t] = ~0ull;
        }
        wsync();

        // ---- dual 128-element register bitonic sort ----
        {
            unsigned long long va = A0w[lane], vb = A0w[lane + 64];
            unsigned long long wa = A1w[lane], wb = A1w[lane + 64];
            #pragma unroll
            for (int size = 2; size <= 128; size <<= 1) {
                #pragma unroll
                for (int stride = 64; stride > 0; stride >>= 1) {
                    if (stride >= size) continue;
                    if (stride == 64) {
                        unsigned long long mn = va < vb ? va : vb;
                        unsigned long long mx = va < vb ? vb : va;
                        va = mn; vb = mx;
                        mn = wa < wb ? wa : wb;
                        mx = wa < wb ? wb : wa;
                        wa = mn; wb = mx;
                    } else {
                        bool keep_lo = (lane & stride) == 0;
                        bool asc0 = ((lane & size) == 0);
                        bool asc1 = (((lane + 64) & size) == 0);
                        unsigned long long oa = __shfl_xor(va, stride, 64);
                        unsigned long long ob = __shfl_xor(vb, stride, 64);
                        va = (asc0 == keep_lo) ? (va < oa ? va : oa) : (va > oa ? va : oa);
                        vb = (asc1 == keep_lo) ? (vb < ob ? vb : ob) : (vb > ob ? vb : ob);
                        oa = __shfl_xor(wa, stride, 64);
                        ob = __shfl_xor(wb, stride, 64);
                        wa = (asc0 == keep_lo) ? (wa < oa ? wa : oa) : (wa > oa ? wa : oa);
                        wb = (asc1 == keep_lo) ? (wb < ob ? wb : ob) : (wb > ob ? wb : ob);
                    }
                }
            }
            A0w[lane] = va; A0w[lane + 64] = vb;
            A1w[lane] = wa; A1w[lane + 64] = wb;
        }
        wsync();

        // ---- radial features 1/(d+eps) ----
        for (int t = lane; t < NNB; t += 64) {
            unsigned long long k = (t < SEL0) ? A0w[t] : A1w[t - SEL0];
            float d; int j; decode(k, d, j);
            sdescw[t] = 1.0f / (d + FEPS);
        }

        // ---- local frame (lane 0) ----
        float f_ld0 = 1.0f, f_ld1 = 1.0f; int f_j0 = -1, f_j1 = -1;
        float r0x=0,r0y=0,r0z=0, r1x=0,r1y=0,r1z=0;
        float u0x=0,u0y=0,u0z=0, u1x=0,u1y=0,u1z=0;
        float f_s=0, f_n2=1, f_n3=1;
        float e2x=0,e2y=0,e2z=0, e3x=0,e3y=0,e3z=0;
        if (lane == 0) {
            float da0, da1, db0, db1; int ja0, ja1, jb0, jb1;
            decode(A0w[0], da0, ja0);
            decode(A0w[1], da1, ja1);
            decode(A1w[0], db0, jb0);
            decode(A1w[1], db1, jb1);
            f_ld0 = (db0 < da0) ? db0 : da0;  f_j0 = (db0 < da0) ? jb0 : ja0;
            f_ld1 = (db1 < da1) ? db1 : da1;  f_j1 = (db1 < da1) ? jb1 : ja1;
            if (f_j0 < 0) f_j0 = i;
            if (f_j1 < 0) f_j1 = i;
            u0x = mimg(xi - X[3*f_j0+0], box, ibox);
            u0y = mimg(yi - X[3*f_j0+1], box, ibox);
            u0z = mimg(zi - X[3*f_j0+2], box, ibox);
            u1x = mimg(xi - X[3*f_j1+0], box, ibox);
            u1y = mimg(yi - X[3*f_j1+1], box, ibox);
            u1z = mimg(zi - X[3*f_j1+2], box, ibox);
            float id0 = 1.0f/(f_ld0 + FEPS), id1 = 1.0f/(f_ld1 + FEPS);
            r0x = u0x*id0; r0y = u0y*id0; r0z = u0z*id0;
            r1x = u1x*id1; r1y = u1y*id1; r1z = u1z*id1;
            f_s = r0x*r1x + r0y*r1y + r0z*r1z;
            float v2x = r1x - f_s*r0x, v2y = r1y - f_s*r0y, v2z = r1z - f_s*r0z;
            f_n2 = sqrtf(v2x*v2x + v2y*v2y + v2z*v2z);
            e2x = v2x/f_n2; e2y = v2y/f_n2; e2z = v2z/f_n2;
            float cx = r0y*r1z - r0z*r1y;
            float cy = r0z*r1x - r0x*r1z;
            float cz = r0x*r1y - r0y*r1x;
            f_n3 = sqrtf(cx*cx + cy*cy + cz*cz);
            e3x = cx/f_n3; e3y = cy/f_n3; e3z = cz/f_n3;
            sAw[0]=r0x; sAw[1]=r0y; sAw[2]=r0z;
            sAw[3]=e2x; sAw[4]=e2y; sAw[5]=e2z;
            sAw[6]=e3x; sAw[7]=e3y; sAw[8]=e3z;
        }
        wsync();

        // ---- angular features: f = (A . dm) / (d+eps)^2 ----
        if (lane < NANG) {
            int slot = (lane < ASEL0) ? lane : SEL0 + (lane - ASEL0);
            unsigned long long k = (slot < SEL0) ? A0w[slot] : A1w[slot - SEL0];
            float d; int j; decode(k, d, j);
            float dx = 0, dy = 0, dz = 0;
            if (j >= 0) {
                dx = mimg(xi - X[3*j+0], box, ibox);
                dy = mimg(yi - X[3*j+1], box, ibox);
                dz = mimg(zi - X[3*j+2], box, ibox);
            }
            float de = d + FEPS;
            float q = 1.0f/(de*de);
            float wx = sAw[0]*dx + sAw[1]*dy + sAw[2]*dz;
            float wy = sAw[3]*dx + sAw[4]*dy + sAw[5]*dz;
            float wz = sAw[6]*dx + sAw[7]*dy + sAw[8]*dz;
            sdescw[NNB + 3*lane + 0] = wx*q;
            sdescw[NNB + 3*lane + 1] = wy*q;
            sdescw[NNB + 3*lane + 2] = wz*q;
        }
        wsync();

        // ---- MLP forward + backward: lane = neuron ----
        const float* W0 = ti ? W0b : W0a;  const float* B0 = ti ? B0b : B0a;
        const float* W1 = ti ? W1b : W1a;  const float* B1 = ti ? B1b : B1a;
        const float* W2 = ti ? W2b : W2a;  const float* B2 = ti ? B2b : B2a;

        float a0 = 0.0f, a1 = 0.0f, a2 = 0.0f, a3 = 0.0f;
        for (int d = 0; d < DDIM - 2; d += 4) {
            a0 = fmaf(sdescw[d+0], W0[(d+0)*HID + lane], a0);
            a1 = fmaf(sdescw[d+1], W0[(d+1)*HID + lane], a1);
            a2 = fmaf(sdescw[d+2], W0[(d+2)*HID + lane], a2);
            a3 = fmaf(sdescw[d+3], W0[(d+3)*HID + lane], a3);
        }
        a0 = fmaf(sdescw[DDIM-2], W0[(DDIM-2)*HID + lane], a0);
        a1 = fmaf(sdescw[DDIM-1], W0[(DDIM-1)*HID + lane], a1);
        float h1 = tanhf(B0[lane] + ((a0 + a1) + (a2 + a3)));
        sh1w[lane] = h1;
        wsync();

        float acc2 = B1[lane];
        #pragma unroll
        for (int m = 0; m < HID; ++m) acc2 = fmaf(sh1w[m], W1[m*HID + lane], acc2);
        float h2 = tanhf(acc2);
        float w2v = W2[lane];
        float part = h2 * w2v;
        #pragma unroll
        for (int o = 32; o > 0; o >>= 1) part += __shfl_down(part, o, 64);
        if (lane == 0) {
            if (lmode) atomicAdd(&sF[SFE], part + B2[0]);
            else       atomicAdd(&out[b], part + B2[0]);
        }
        float dh2 = (1.0f - h2*h2) * w2v;
        sdh1w[lane] = dh2;
        wsync();

        float accb = 0.0f;
        #pragma unroll
        for (int m = 0; m < HID; ++m) accb = fmaf(W1[lane*HID + m], sdh1w[m], accb);
        wsync();
        float dh1 = (1.0f - h1*h1) * accb;
        sdh1w[lane] = dh1;
        wsync();

        for (int d = lane; d < DDIM; d += 64) {
            float a = 0.0f;
            #pragma unroll
            for (int m = 0; m < HID; ++m) a = fmaf(W0[d*HID + m], sdh1w[m], a);
            sgw[d] = a;
        }
        wsync();

        // ---- gradient scatter into LDS (lmode) or global (fallback) ----
        float rG[9];
        #pragma unroll
        for (int q9 = 0; q9 < 9; ++q9) rG[q9] = 0.0f;
        float fix = 0.0f, fiy = 0.0f, fiz = 0.0f;

        for (int t = lane; t < NNB; t += 64) {
            unsigned long long k = (t < SEL0) ? A0w[t] : A1w[t - SEL0];
            float d; int j; decode(k, d, j);
            if (j >= 0) {
                float dx = mimg(xi - X[3*j+0], box, ibox);
                float dy = mimg(yi - X[3*j+1], box, ibox);
                float dz = mimg(zi - X[3*j+2], box, ibox);
                float gr = sgw[t];
                float de = d + FEPS;
                float coef = -gr / (d * de * de);
                float gx = coef*dx, gy = coef*dy, gz = coef*dz;
                int a = -1;
                if (t < ASEL0) a = t;
                else if (t >= SEL0 && t < SEL0 + ASEL1) a = ASEL0 + (t - SEL0);
                if (a >= 0) {
                    float q = 1.0f/(de*de);
                    float gax = sgw[NNB+3*a+0], gay = sgw[NNB+3*a+1], gaz = sgw[NNB+3*a+2];
                    float wx = sAw[0]*dx + sAw[1]*dy + sAw[2]*dz;
                    float wy = sAw[3]*dx + sAw[4]*dy + sAw[5]*dz;
                    float wz = sAw[6]*dx + sAw[7]*dy + sAw[8]*dz;
                    float tx = sAw[0]*gax + sAw[3]*gay + sAw[6]*gaz;
                    float ty = sAw[1]*gax + sAw[4]*gay + sAw[7]*gaz;
                    float tz = sAw[2]*gax + sAw[5]*gay + sAw[8]*gaz;
                    float gw = gax*wx + gay*wy + gaz*wz;
                    float c2 = -2.0f * gw * q / (de * d);
                    gx += q*tx + c2*dx;
                    gy += q*ty + c2*dy;
                    gz += q*tz + c2*dz;
                    rG[0] += gax*dx*q; rG[1] += gax*dy*q; rG[2] += gax*dz*q;
                    rG[3] += gay*dx*q; rG[4] += gay*dy*q; rG[5] += gay*dz*q;
                    rG[6] += gaz*dx*q; rG[7] += gaz*dy*q; rG[8] += gaz*dz*q;
                }
                if (lmode) {
                    atomicAdd(&sF[3*j+0], gx);
                    atomicAdd(&sF[3*j+1], gy);
                    atomicAdd(&sF[3*j+2], gz);
                } else {
                    atomicAdd(&Fg[3*j+0], gx);
                    atomicAdd(&Fg[3*j+1], gy);
                    atomicAdd(&Fg[3*j+2], gz);
                }
                fix -= gx; fiy -= gy; fiz -= gz;
            }
        }

        // wave-reduce frame gradients + self-force to lane 0
        #pragma unroll
        for (int o = 32; o > 0; o >>= 1) {
            #pragma unroll
            for (int q9 = 0; q9 < 9; ++q9) rG[q9] += __shfl_down(rG[q9], o, 64);
            fix += __shfl_down(fix, o, 64);
            fiy += __shfl_down(fiy, o, 64);
            fiz += __shfl_down(fiz, o, 64);
        }

        // ---- frame backward + self-force (lane 0) ----
        if (lane == 0) {
            float g0x=rG[0], g0y=rG[1], g0z=rG[2];
            float g2x=rG[3], g2y=rG[4], g2z=rG[5];
            float g3x=rG[6], g3y=rG[7], g3z=rG[8];
            float d3 = g3x*e3x + g3y*e3y + g3z*e3z;
            float in3 = 1.0f/f_n3;
            float dcx = (g3x - d3*e3x)*in3;
            float dcy = (g3y - d3*e3y)*in3;
            float dcz = (g3z - d3*e3z)*in3;
            float gr0x = r1y*dcz - r1z*dcy;
            float gr0y = r1z*dcx - r1x*dcz;
            float gr0z = r1x*dcy - r1y*dcx;
            float gr1x = dcy*r0z - dcz*r0y;
            float gr1y = dcz*r0x - dcx*r0z;
            float gr1z = dcx*r0y - dcy*r0x;
            float d2 = g2x*e2x + g2y*e2y + g2z*e2z;
            float in2 = 1.0f/f_n2;
            float dvx = (g2x - d2*e2x)*in2;
            float dvy = (g2y - d2*e2y)*in2;
            float dvz = (g2z - d2*e2z)*in2;
            gr1x += dvx; gr1y += dvy; gr1z += dvz;
            gr0x -= f_s*dvx; gr0y -= f_s*dvy; gr0z -= f_s*dvz;
            float dss = -(dvx*r0x + dvy*r0y + dvz*r0z);
            gr0x += dss*r1x; gr0y += dss*r1y; gr0z += dss*r1z;
            gr1x += dss*r0x; gr1y += dss*r0y; gr1z += dss*r0z;
            gr0x += g0x; gr0y += g0y; gr0z += g0z;
            float de0 = f_ld0 + FEPS;
            float dot0 = gr0x*u0x + gr0y*u0y + gr0z*u0z;
            float k0 = dot0 / (f_ld0 * de0 * de0);
            float gu0x = gr0x/de0 - k0*u0x;
            float gu0y = gr0y/de0 - k0*u0y;
            float gu0z = gr0z/de0 - k0*u0z;
            float de1 = f_ld1 + FEPS;
            float dot1 = gr1x*u1x + gr1y*u1y + gr1z*u1z;
            float k1 = dot1 / (f_ld1 * de1 * de1);
            float gu1x = gr1x/de1 - k1*u1x;
            float gu1y = gr1y/de1 - k1*u1y;
            float gu1z = gr1z/de1 - k1*u1z;
            fix -= gu0x + gu1x;
            fiy -= gu0y + gu1y;
            fiz -= gu0z + gu1z;
            if (lmode) {
                atomicAdd(&sF[3*f_j0+0], gu0x); atomicAdd(&sF[3*f_j0+1], gu0y); atomicAdd(&sF[3*f_j0+2], gu0z);
                atomicAdd(&sF[3*f_j1+0], gu1x); atomicAdd(&sF[3*f_j1+1], gu1y); atomicAdd(&sF[3*f_j1+2], gu1z);
                atomicAdd(&sF[3*i+0], fix);     atomicAdd(&sF[3*i+1], fiy);     atomicAdd(&sF[3*i+2], fiz);
            } else {
                atomicAdd(&Fg[3*f_j0+0], gu0x); atomicAdd(&Fg[3*f_j0+1], gu0y); atomicAdd(&Fg[3*f_j0+2], gu0z);
                atomicAdd(&Fg[3*f_j1+0], gu1x); atomicAdd(&Fg[3*f_j1+1], gu1y); atomicAdd(&Fg[3*f_j1+2], gu1z);
                atomicAdd(&Fg[3*i+0], fix);     atomicAdd(&Fg[3*i+1], fiy);     atomicAdd(&Fg[3*i+2], fiz);
            }
        }
    } // atom valid

    // ---- flush block force accumulator to its private slot ----
    __syncthreads();
    if (lmode) {
        float* slotp = slotbase + (size_t)blockIdx.x * sstride;
        for (int s2 = threadIdx.x; s2 < 3*N; s2 += BLOCK) slotp[s2] = sF[s2];
        if (threadIdx.x == 0) slotp[3*N] = sF[SFE];
    }
}

extern "C" void kernel_launch(void* const* d_in, const int* in_sizes, int n_in,
                              void* d_out, int out_size, void* d_ws, size_t ws_size,
                              hipStream_t stream) {
    const float* xyz  = (const float*)d_in[0];
    const int*   types = (const int*)d_in[1];
    const void*  boxp = d_in[2];
    int BN = in_sizes[1];              // B*N
    int B = out_size - 3*BN;           // out = energy(B) + forces(3*B*N)
    if (B < 1) B = 1;
    int N = BN / B;

    // lmode: 8 atoms (one batch) per block, per-block slot in workspace
    int sstride = 3 * N + 32;
    bool ok = (N <= NMAX) && (N % WPB == 0) && (BN % WPB == 0) &&
              ((size_t)(BN / WPB) * sstride * sizeof(float) <= ws_size);

    // out is accumulated atomically (reduce partials / fallback) -> zero it
    hipMemsetAsync(d_out, 0, (size_t)out_size * sizeof(float), stream);

    if (ok) {
        float* rep = (float*)d_ws;
        int nblk = BN / WPB;           // 512 blocks at B=2,N=2048
        md_kernel<<<dim3(nblk), dim3(BLOCK), 0, stream>>>(
            xyz, types, boxp,
            (const float*)d_in[3],  (const float*)d_in[4],
            (const float*)d_in[5],  (const float*)d_in[6],
            (const float*)d_in[7],  (const float*)d_in[8],
            (const float*)d_in[9],  (const float*)d_in[10],
            (const float*)d_in[11], (const float*)d_in[12],
            (const float*)d_in[13], (const float*)d_in[14],
            (float*)d_out, rep, sstride, B, N);
        int nspb = N / WPB;            // slots per batch
        int ngroups = (nspb < RGROUPS) ? nspb : RGROUPS;
        int rgs = (nspb + ngroups - 1) / ngroups;
        int nb = (out_size + 255) / 256;
        reduce_kernel<<<dim3(nb, ngroups), dim3(256), 0, stream>>>(
            rep, (float*)d_out, out_size, B, N, sstride, nspb, rgs);
    } else {
        // fallback: device-scope atomics straight into out
        int nblk = (BN + WPB - 1) / WPB;
        md_kernel<<<dim3(nblk), dim3(BLOCK), 0, stream>>>(
            xyz, types, boxp,
            (const float*)d_in[3],  (const float*)d_in[4],
            (const float*)d_in[5],  (const float*)d_in[6],
            (const float*)d_in[7],  (const float*)d_in[8],
            (const float*)d_in[9],  (const float*)d_in[10],
            (const float*)d_in[11], (const float*)d_in[12],
            (const float*)d_in[13], (const float*)d_in[14],
            (float*)d_out, nullptr, 0, B, N);
    }
}